// Round 1
// baseline (216.058 us; speedup 1.0000x reference)
//
#include <hip/hip_runtime.h>

// Banded stereo cost volume: cost[j,h,x] = sum_c L[c,h,x] * R[c,h,x-j], 0 if x<j.
// C=32 fixed. Tile: TJ=128 j  x  TX=128 x per block, one h per block.
// 256 threads, each computes an 8j x 8x register tile.

#define TX 128
#define TJ 128
#define NC 32

// XOR swizzle of float4-chunk index within a row to break LDS bank conflicts.
__device__ __forceinline__ int swz64(int q) { return q ^ ((q >> 3) & 7); } // rows of 64 chunks
__device__ __forceinline__ int swz32(int q) { return q ^ ((q >> 3) & 3); } // rows of 32 chunks

__global__ __launch_bounds__(256, 3)
void cost_volume_kernel(const float* __restrict__ L,
                        const float* __restrict__ R,
                        float* __restrict__ out,
                        int H, int W, int D)
{
    __shared__ float Ls[NC * TX];        // 16 KB: L[c][x0 + 0..127]
    __shared__ float Rs[NC * (TX + TJ)]; // 32 KB: R[c][x0-j0-128 .. +255] (zero-padded OOB)

    const int x0 = blockIdx.x * TX;
    const int j0 = blockIdx.y * TJ;
    const int h  = blockIdx.z;
    const int t  = threadIdx.x;
    const int tx = t & 15;   // x-block 8*tx
    const int ty = t >> 4;   // j-block 8*ty

    const int jbase = j0 + ty * 8;
    const int xb    = x0 + tx * 8;

    // Fast path: entire tile has x < j -> zeros.
    if (x0 + TX - 1 < j0) {
        const float4 z = make_float4(0.f, 0.f, 0.f, 0.f);
        #pragma unroll
        for (int jj = 0; jj < 8; ++jj) {
            int j = jbase + jj;
            if (j < D) {
                float* p = out + ((size_t)j * H + h) * W + xb;
                *(float4*)(p)     = z;
                *(float4*)(p + 4) = z;
            }
        }
        return;
    }

    // ---- stage tiles into LDS (float4, coalesced, swizzled) ----
    {
        const size_t rowL = (size_t)H * W; // stride between channels
        #pragma unroll
        for (int k = 0; k < 4; ++k) {
            int f = t + k * 256;           // float4 id, 1024 total
            int c = f >> 5;                // 32 float4 per L row
            int q = f & 31;
            float4 v = *(const float4*)(L + (size_t)c * rowL + (size_t)h * W + x0 + 4 * q);
            *(float4*)&Ls[c * TX + 4 * swz32(q)] = v;
        }
        const int gbase = x0 - j0 - TJ;    // multiple of 128 -> aligned
        #pragma unroll
        for (int k = 0; k < 8; ++k) {
            int f = t + k * 256;           // float4 id, 2048 total
            int c = f >> 6;                // 64 float4 per R row
            int q = f & 63;
            int g = gbase + 4 * q;
            float4 v = make_float4(0.f, 0.f, 0.f, 0.f);
            if (g >= 0 && g < W)           // g,W multiples of 4 -> whole float4 in/out
                v = *(const float4*)(R + (size_t)c * rowL + (size_t)h * W + g);
            *(float4*)&Rs[c * (TX + TJ) + 4 * swz64(q)] = v;
        }
    }
    __syncthreads();

    // Waves whose whole j range is past D: done (no more barriers below).
    if (jbase >= D) return;

    // ---- register-tiled compute: 8 j x 8 x per thread ----
    float acc[8][8];
    #pragma unroll
    for (int jj = 0; jj < 8; ++jj)
        #pragma unroll
        for (int xx = 0; xx < 8; ++xx) acc[jj][xx] = 0.f;

    // Logical offsets (c-invariant): L chunks 2tx, 2tx+1; R chunks qr0..qr0+3
    // where s0 = 8*(tx-ty) + (TJ-8) = 4*qr0; r[i] == Rs_logical[s0+i].
    const int lo0 = 4 * swz32(2 * tx);
    const int lo1 = 4 * swz32(2 * tx + 1);
    const int qr0 = 2 * (tx - ty) + 30;
    const int ro0 = 4 * swz64(qr0 + 0);
    const int ro1 = 4 * swz64(qr0 + 1);
    const int ro2 = 4 * swz64(qr0 + 2);
    const int ro3 = 4 * swz64(qr0 + 3);

    #pragma unroll 2
    for (int c = 0; c < NC; ++c) {
        const float* Lc = Ls + c * TX;
        const float* Rc = Rs + c * (TX + TJ);
        float l[8], r[16];
        *(float4*)&l[0]  = *(const float4*)(Lc + lo0);
        *(float4*)&l[4]  = *(const float4*)(Lc + lo1);
        *(float4*)&r[0]  = *(const float4*)(Rc + ro0);
        *(float4*)&r[4]  = *(const float4*)(Rc + ro1);
        *(float4*)&r[8]  = *(const float4*)(Rc + ro2);
        *(float4*)&r[12] = *(const float4*)(Rc + ro3);
        #pragma unroll
        for (int jj = 0; jj < 8; ++jj)
            #pragma unroll
            for (int xx = 0; xx < 8; ++xx)
                acc[jj][xx] = fmaf(l[xx], r[xx - jj + 8], acc[jj][xx]);
    }

    // ---- store (x<j region is exact 0 via zero-padded Rs) ----
    #pragma unroll
    for (int jj = 0; jj < 8; ++jj) {
        int j = jbase + jj;
        if (j < D) {
            float* p = out + ((size_t)j * H + h) * W + xb;
            *(float4*)(p)     = make_float4(acc[jj][0], acc[jj][1], acc[jj][2], acc[jj][3]);
            *(float4*)(p + 4) = make_float4(acc[jj][4], acc[jj][5], acc[jj][6], acc[jj][7]);
        }
    }
}

extern "C" void kernel_launch(void* const* d_in, const int* in_sizes, int n_in,
                              void* d_out, int out_size, void* d_ws, size_t ws_size,
                              hipStream_t stream)
{
    const float* L0 = (const float*)d_in[0];
    const float* R0 = (const float*)d_in[1];
    const float* L1 = (const float*)d_in[2];
    const float* R1 = (const float*)d_in[3];
    const float* L2 = (const float*)d_in[4];
    const float* R2 = (const float*)d_in[5];
    float* out = (float*)d_out;

    dim3 blk(256);
    // scale 0: H=256, W=512, D=192
    cost_volume_kernel<<<dim3(512 / TX, (192 + TJ - 1) / TJ, 256), blk, 0, stream>>>(
        L0, R0, out, 256, 512, 192);
    out += (size_t)192 * 256 * 512;
    // scale 1: H=128, W=256, D=96
    cost_volume_kernel<<<dim3(256 / TX, (96 + TJ - 1) / TJ, 128), blk, 0, stream>>>(
        L1, R1, out, 128, 256, 96);
    out += (size_t)96 * 128 * 256;
    // scale 2: H=64, W=128, D=48
    cost_volume_kernel<<<dim3(128 / TX, (48 + TJ - 1) / TJ, 64), blk, 0, stream>>>(
        L2, R2, out, 64, 128, 48);
}